// Round 5
// baseline (164.334 us; speedup 1.0000x reference)
//
#include <hip/hip_runtime.h>
#include <cstddef>

#define NEXP    45
#define DIM     256
#define KCH     64     // output dims per block (lane = k)
#define NTOK    4096
#define HALF    2048   // token-split factor 2
#define GRP     8      // tokens per wave-group (W register reuse x8)
#define NWAVE   8
#define LISTCAP 1024   // m per (expert, half) ~46 +- 7; 1024 is >50 sigma safe

// Zero d_out (harness re-poisons to 0xAA before every timed launch; first
// correctness call's d_out state is unspecified -> must zero explicitly).
__global__ void pos_zero_kernel(float* out) { out[threadIdx.x] = 0.0f; }

// Grid: 45 experts * 4 out-chunks * 2 token-halves = 360 blocks, 512 threads.
// R4 post-mortem fixes vs R3 (78us, VALUBusy 11%, SGPR 112 maxed):
//  - x loads forced onto the VECTOR path (per-lane VGPR address via asm
//    uniformity-break). R3's readfirstlane made them s_load_dwordx4: scalar
//    results are out-of-order (use requires lgkmcnt(0)) and 48 in-flight
//    results need 192 SGPRs >> 112 budget -> ~1 load in flight -> one ~300cy
//    stall per d0 vs 48cy of FMA = the measured 11% VALUBusy.
//  - LDS 82.5KB -> 70KB (list 4096->1024) -> 2 blocks/CU instead of 1.
//  - token-split x2 -> 360 blocks, all co-resident -> ~2.8 waves/SIMD.
__global__ __launch_bounds__(512, 4)
void pos_expert_kernel(const float* __restrict__ x, const int* __restrict__ tags,
                       const float* __restrict__ W, const float* __restrict__ bias,
                       float* __restrict__ out) {
  __shared__ alignas(16) float WT[64 * DIM];   // [d0][k][c] = W[e][k0+k][4*d0+c], 64 KB
  __shared__ int   list[LISTCAP];              // 4 KB
  __shared__ float wmax[NWAVE][KCH];           // 2 KB
  __shared__ int   cnt;

  const int tid  = threadIdx.x;
  const int lane = tid & 63;
  const int wv   = tid >> 6;
  const int e    = blockIdx.x >> 3;
  const int sub  = blockIdx.x & 7;
  const int k0   = (sub >> 1) * KCH;
  const int n0   = (sub & 1) * HALF;

  if (tid == 0) cnt = 0;
  __syncthreads();

  // ---- compact this expert's token indices within our half (order irrelevant
  // under max). Index masked so even an impossible overflow can't write OOB.
  for (int n = n0 + tid; n < n0 + HALF; n += 512) {
    if (tags[n] == e) list[atomicAdd(&cnt, 1) & (LISTCAP - 1)] = n;
  }

  // ---- stage W chunk transposed. Thread = (row k=lane, col-block d0=wv*8+r).
  // ds_write_b128 at byte (d0*64+lane)*16: per-lane-contiguous -> conflict-free.
  {
    const float* Wrow = W + ((size_t)e * DIM + k0 + lane) * DIM;
#pragma unroll
    for (int r = 0; r < 8; ++r) {
      const int d0 = (wv << 3) + r;
      const float4 v = *(const float4*)(Wrow + (d0 << 2));
      *(float4*)&WT[((d0 << 6) + lane) << 2] = v;
    }
  }
  __syncthreads();   // covers list/cnt (compaction) and WT (staging)

  const int   m  = cnt;
  const float bk = bias[(size_t)e * DIM + k0 + lane];
  float mx = 0.0f;   // relu floor: every contribution is max'ed against 0

  for (int g0 = wv * GRP; g0 < m; g0 += NWAVE * GRP) {
    const int nt = (m - g0 < GRP) ? (m - g0) : GRP;

    // Per-token row pointers. asm breaks uniformity analysis -> n lives in a
    // VGPR -> global_load_dwordx4 (in-order vmcnt, VGPR results, pipelineable)
    // instead of out-of-order s_load choking on the SGPR budget.
    const float4* xp[GRP];
#pragma unroll
    for (int j = 0; j < GRP; ++j) {
      int n = list[g0 + ((j < nt) ? j : 0)];   // tail: duplicate token 0, discarded below
      asm volatile("" : "+v"(n));
      xp[j] = (const float4*)(x + (size_t)n * DIM);
    }

    float a[GRP];
#pragma unroll
    for (int j = 0; j < GRP; ++j) a[j] = 0.0f;

    // Per d0: 1 ds_read_b128 (imm offset) + 8 broadcast global_load_dwordx4
    // (imm offsets, same line across lanes) + 32 FMA-instr. W reused x8 from
    // registers keeps W-LDS traffic at ~75% of the per-CU FMA wall.
#pragma unroll 4
    for (int d0 = 0; d0 < 64; ++d0) {
      const float4 w4 = *(const float4*)&WT[((d0 << 6) + lane) << 2];
#pragma unroll
      for (int j = 0; j < GRP; ++j) {
        const float4 xv = xp[j][d0];
        a[j] += w4.x * xv.x + w4.y * xv.y + w4.z * xv.z + w4.w * xv.w;
      }
    }

#pragma unroll
    for (int j = 0; j < GRP; ++j)
      if (j < nt) mx = fmaxf(mx, a[j] + bk);
  }

  wmax[wv][lane] = mx;
  __syncthreads();
  if (tid < KCH) {
    float v = wmax[0][tid];
#pragma unroll
    for (int w = 1; w < NWAVE; ++w) v = fmaxf(v, wmax[w][tid]);
    // all values >= 0: int-bit compare is monotone; out zeroed by pos_zero_kernel
    atomicMax((int*)out + k0 + tid, __float_as_int(v));
  }
}

extern "C" void kernel_launch(void* const* d_in, const int* in_sizes, int n_in,
                              void* d_out, int out_size, void* d_ws, size_t ws_size,
                              hipStream_t stream) {
  const float* x    = (const float*)d_in[0];
  const int*   tags = (const int*)d_in[1];
  const float* W    = (const float*)d_in[2];
  const float* b    = (const float*)d_in[3];
  float*       out  = (float*)d_out;

  pos_zero_kernel<<<1, 256, 0, stream>>>(out);
  pos_expert_kernel<<<NEXP * 8, 512, 0, stream>>>(x, tags, W, b, out);
}

// Round 8
// 107.776 us; speedup vs baseline: 1.5248x; 1.5248x over previous
//
#include <hip/hip_runtime.h>
#include <cstddef>
#include <math.h>

#define NEXP    45
#define DIM     256
#define NTOK    4096
#define HALF    2048   // token-split factor 2
#define KQ      64     // k-range per block (quarter of DIM)
#define KW      8      // k's per wave (8 waves x 8 = 64)
#define CHUNK   64     // tokens per staged chunk (lane = token)
#define LISTCAP 128    // m per (expert, half) ~45.5 +- 6.7; 128 is >12 sigma safe

// Zero d_out (harness re-poisons to 0xAA before every timed launch).
__global__ void pos_zero_kernel(float* out) { out[threadIdx.x] = 0.0f; }

// Structure (R4 scalar-starve + R5 spill post-mortems): lane = TOKEN, not k.
// Per block (expert e, k-quarter, token-half): compact token list, then per
// 64-token chunk: stage x rows in LDS (XOR-swizzled quads -> write AND read
// at the b128 8-words/bank floor), each wave streams its 8 W rows through
// SGPRs (s_load_dwordx4, wave-uniform base) and FMAs v_fmac(vacc, s_w, v_x).
// Token-max = 6-step shfl_xor butterfly per k; bias commutes past max, added
// once. No per-iteration VMEM on the critical path, no LDS broadcasts, no
// VGPR blowup. Grid 360 blocks (token-split x2) so no CU idles; doubled-up
// CUs co-reside 2 blocks (~130KB LDS) = 4 waves/SIMD to hide the
// per-iteration s_load/ds_read lgkmcnt drain (the known residual risk).
__global__ __launch_bounds__(512, 4)
void pos_expert_kernel(const float* __restrict__ x, const int* __restrict__ tags,
                       const float* __restrict__ W, const float* __restrict__ bias,
                       float* __restrict__ out) {
  __shared__ alignas(16) float xs[CHUNK * DIM];   // 64 KB, XOR-swizzled quads
  __shared__ int list[LISTCAP];
  __shared__ int cnt;

  const int tid  = threadIdx.x;
  const int lane = tid & 63;
  const int wv   = __builtin_amdgcn_readfirstlane(tid >> 6);
  const int e    = blockIdx.x >> 3;
  const int sub  = blockIdx.x & 7;
  const int kq   = (sub >> 1) * KQ;
  const int n0   = (sub & 1) * HALF;

  if (tid == 0) cnt = 0;
  __syncthreads();

  // ---- compact this expert's token indices in our half (order irrelevant
  // under max; write index masked so even impossible overflow stays in-bounds)
  for (int n = n0 + tid; n < n0 + HALF; n += 512)
    if (tags[n] == e) list[atomicAdd(&cnt, 1) & (LISTCAP - 1)] = n;
  __syncthreads();
  const int m = cnt;

  // Wave-uniform W base for this wave's 8 rows -> s_load_dwordx4 (SGPR base +
  // uniform offset, scalar pipe; data parks in SGPRs, free VALU operand).
  const float* Wb = W + ((size_t)(e * DIM + kq + wv * KW)) * DIM;

  float mx[KW];
#pragma unroll
  for (int j = 0; j < KW; ++j) mx[j] = -INFINITY;

  for (int c0 = 0; c0 < m; c0 += CHUNK) {
    // ---- stage chunk: thread = (row r=tid>>3, col-slice c=tid&7). For fixed
    // i, 8 consecutive threads read 128 contiguous bytes of a row (coalesced).
    // LDS write of quad q at slot q^r: exactly 8 words/bank = b128 floor.
    {
      const int r = tid >> 3, c = tid & 7;
      int idx = c0 + r; if (idx >= m) idx = m - 1;   // clamp: dup token, max-idempotent
      const int tok = list[idx];
      const float4* src = (const float4*)(x + (size_t)tok * DIM);
#pragma unroll
      for (int i = 0; i < 8; ++i) {
        const int q  = i * 8 + c;
        const int qs = q ^ r;
        *(float4*)&xs[((r << 6) + qs) << 2] = src[q];
      }
    }
    __syncthreads();

    const bool valid = (c0 + lane) < m;
    float acc[KW];
#pragma unroll
    for (int j = 0; j < KW; ++j) acc[j] = 0.0f;

    // 1-deep double buffer: x quad (VGPR, ds_read_b128) + 8 W quads (SGPRs).
    float4 xc = *(const float4*)&xs[((lane << 6) + (0 ^ lane)) << 2];
    float4 swc[KW], swn[KW];
#pragma unroll
    for (int j = 0; j < KW; ++j) swc[j] = *(const float4*)(Wb + j * DIM);

#pragma unroll 4
    for (int dc = 0; dc < 64; ++dc) {
      const int dn = (dc + 1) & 63;   // branch-free wrap; wrap loads unused
      const float4 xn = *(const float4*)&xs[((lane << 6) + (dn ^ lane)) << 2];
#pragma unroll
      for (int j = 0; j < KW; ++j)
        swn[j] = *(const float4*)(Wb + j * DIM + (dn << 2));
#pragma unroll
      for (int j = 0; j < KW; ++j)
        acc[j] += xc.x * swc[j].x + xc.y * swc[j].y + xc.z * swc[j].z + xc.w * swc[j].w;
      xc = xn;
#pragma unroll
      for (int j = 0; j < KW; ++j) swc[j] = swn[j];
    }

    // token-max: 6-step butterfly over 64 lanes per k
#pragma unroll
    for (int j = 0; j < KW; ++j) {
      float v = valid ? acc[j] : -INFINITY;
#pragma unroll
      for (int s = 1; s < 64; s <<= 1) v = fmaxf(v, __shfl_xor(v, s, 64));
      mx[j] = fmaxf(mx[j], v);
    }
    __syncthreads();   // xs reused next chunk
  }

  // route mx[j] (wave-uniform after butterfly) to lane j; bias + relu + atomicMax
  float v = mx[0];
#pragma unroll
  for (int j = 1; j < KW; ++j) if (lane == j) v = mx[j];
  if (lane < KW) {
    const int kk = kq + wv * KW + lane;
    const float y = fmaxf(v + bias[e * DIM + kk], 0.0f);   // m==0 -> -inf -> 0 (no-op)
    atomicMax((int*)out + kk, __float_as_int(y));          // >=0: int order monotone
  }
}

extern "C" void kernel_launch(void* const* d_in, const int* in_sizes, int n_in,
                              void* d_out, int out_size, void* d_ws, size_t ws_size,
                              hipStream_t stream) {
  const float* x    = (const float*)d_in[0];
  const int*   tags = (const int*)d_in[1];
  const float* W    = (const float*)d_in[2];
  const float* b    = (const float*)d_in[3];
  float*       out  = (float*)d_out;

  pos_zero_kernel<<<1, 256, 0, stream>>>(out);
  pos_expert_kernel<<<NEXP * 8, 512, 0, stream>>>(x, tags, W, b, out);
}